// Round 8
// baseline (404.846 us; speedup 1.0000x reference)
//
#include <hip/hip_runtime.h>
#include <hip/hip_bf16.h>
#include <stdint.h>
#include <math.h>

#define NN 16384
#define DD 256
#define MARGIN_F 0.2f

typedef __attribute__((ext_vector_type(8))) short bf16x8;
typedef __attribute__((ext_vector_type(16))) float f32x16;

#define RS 528                      // padded LDS row stride (bytes)
#define BUF1 33792                  // 64 * RS
#define CLDS_OFF 67584              // 128 * RS

__device__ inline short f2bf(float f) {
    __hip_bfloat16 h = __float2bfloat16(f);
    return *reinterpret_cast<short*>(&h);
}

// monotone order-preserving float<->uint key (max via unsigned atomicMax)
__device__ inline unsigned fkey(float f) {
    unsigned b = __float_as_uint(f);
    return (b & 0x80000000u) ? ~b : (b | 0x80000000u);
}
__device__ inline float fdec(unsigned k) {
    return __uint_as_float((k & 0x80000000u) ? (k ^ 0x80000000u) : ~k);
}
#define NEG_INF_KEY 0x007FFFFFu   // fkey(-inf)

// ---------------- fused prep: f32->bf16 + diag + init maxes ----------------
__global__ __launch_bounds__(256) void fused_prep_kernel(
    const float* __restrict__ imgs, const float* __restrict__ caps,
    short* __restrict__ imgsb, short* __restrict__ capsb,
    float* __restrict__ diag, unsigned* __restrict__ rowmax,
    unsigned* __restrict__ colmax) {
    const int i = (blockIdx.x << 2) + (threadIdx.x >> 6);
    const int l = threadIdx.x & 63;
    const float4* a4 = reinterpret_cast<const float4*>(imgs + (size_t)i * DD);
    const float4* b4 = reinterpret_cast<const float4*>(caps + (size_t)i * DD);
    float4 av = a4[l];
    float4 bv = b4[l];
    short4 as, bs;
    as.x = f2bf(av.x); as.y = f2bf(av.y); as.z = f2bf(av.z); as.w = f2bf(av.w);
    bs.x = f2bf(bv.x); bs.y = f2bf(bv.y); bs.z = f2bf(bv.z); bs.w = f2bf(bv.w);
    reinterpret_cast<short4*>(imgsb + (size_t)i * DD)[l] = as;
    reinterpret_cast<short4*>(capsb + (size_t)i * DD)[l] = bs;
    float s = av.x * bv.x + av.y * bv.y + av.z * bv.z + av.w * bv.w;
    #pragma unroll
    for (int off = 32; off > 0; off >>= 1) s += __shfl_down(s, off);
    if (l == 0) {
        diag[i] = s;
        rowmax[i] = NEG_INF_KEY;
        colmax[i] = NEG_INF_KEY;
    }
}

// ---------------- main: A-resident strip kernel, 32x32x16 MFMA -------------
// 512 blocks = 128 row-panels x 4 col-strips. A panel (128x256) -> registers
// via padded LDS. B: 64-col chunks, reg-staged (issue-early/write-late) into
// padded dbuf; ds_read_b128 with immediate ks-offsets (conflict-free, no VALU).
__global__ __launch_bounds__(256, 2) void score_max_kernel(
    const short* __restrict__ imgsb, const short* __restrict__ capsb,
    const float* __restrict__ diag,
    unsigned* __restrict__ rowmax, unsigned* __restrict__ colmax) {

    __shared__ char lds[67840];   // 2x(64*528) A/B region + 64 u32 colmax keys
    unsigned* clds = reinterpret_cast<unsigned*>(lds + CLDS_OFF);

    const int bid   = blockIdx.x;
    const int panel = bid >> 2;
    const int strip = bid & 3;
    const int brow  = panel << 7;
    const int scol  = strip << 12;

    const int t    = threadIdx.x;
    const int wid  = t >> 6;
    const int lane = t & 63;
    const int wr   = wid >> 1;    // 0..1: 64-row half
    const int wc   = wid & 1;     // 0..1: 32-col half of chunk
    const int l5   = lane & 31;
    const int hi   = lane >> 5;

    if (wid == 0) clds[lane] = NEG_INF_KEY;

    // ---- stage A panel (128 rows x 256) via regs into padded LDS ----
    {
        const int rt   = t >> 1;           // 0..127
        const int half = t & 1;
        const int4* src = reinterpret_cast<const int4*>(
            imgsb + ((size_t)(brow + rt) << 8) + (half << 7));
        int4 ar[16];
        #pragma unroll
        for (int j = 0; j < 16; ++j) ar[j] = src[j];
        char* dst = lds + rt * RS + (half << 8);
        #pragma unroll
        for (int j = 0; j < 16; ++j)
            *reinterpret_cast<int4*>(dst + j * 16) = ar[j];
    }
    __syncthreads();

    // ---- A fragments: af[mm][ks], rows wr*64+mm*32+l5, 16B at hi*16+ks*32 --
    bf16x8 af[2][16];
    #pragma unroll
    for (int mm = 0; mm < 2; ++mm) {
        const char* ab = lds + (wr * 64 + mm * 32 + l5) * RS + hi * 16;
        #pragma unroll
        for (int ks = 0; ks < 16; ++ks)
            af[mm][ks] = *reinterpret_cast<const bf16x8*>(ab + ks * 32);
    }
    __syncthreads();   // done reading A before B writes reuse the region

    // ---- B staging geometry: thread t handles row t>>2, quarter t&3 ----
    const int brt = t >> 2;       // 0..63
    const int bq  = t & 3;

    // prologue: issue loads for chunk h=0
    int4 breg[8];
    {
        const int4* s4 = reinterpret_cast<const int4*>(
            capsb + ((size_t)(scol + brt) << 8) + (bq << 6));
        #pragma unroll
        for (int j = 0; j < 8; ++j) breg[j] = s4[j];
    }

    float rmx[2][16];
    #pragma unroll
    for (int mm = 0; mm < 2; ++mm)
        #pragma unroll
        for (int rr = 0; rr < 16; ++rr) rmx[mm][rr] = -INFINITY;

    for (int h = 0; h < 64; ++h) {
        const int cb = scol + (h << 6);

        // bar1: everyone done reading buf[(h+1)&1]; drains loads(h) (vmcnt)
        __syncthreads();

        // wave 0: flush+reset previous chunk's colmax keys
        if (h > 0 && wid == 0) {
            unsigned k = clds[lane];
            atomicMax(&colmax[cb - 64 + lane], k);
            clds[lane] = NEG_INF_KEY;
        }

        // write-late: B(h) regs -> padded LDS
        {
            char* dst = lds + ((h & 1) ? BUF1 : 0) + brt * RS + (bq << 7);
            #pragma unroll
            for (int j = 0; j < 8; ++j)
                *reinterpret_cast<int4*>(dst + j * 16) = breg[j];
        }
        // issue-early: loads for chunk h+1 (fly across the whole compute)
        if (h < 63) {
            const int4* s4 = reinterpret_cast<const int4*>(
                capsb + ((size_t)(cb + 64 + brt) << 8) + (bq << 6));
            #pragma unroll
            for (int j = 0; j < 8; ++j) breg[j] = s4[j];
        }

        asm volatile("s_waitcnt lgkmcnt(0)" ::: "memory");
        __builtin_amdgcn_s_barrier();      // bar2: all B(h) writes visible
        asm volatile("" ::: "memory");
        __builtin_amdgcn_sched_barrier(0);

        // ---- compute: 2 row-tiles x 16 k-steps of 32x32x16 ----
        const char* bb = lds + ((h & 1) ? BUF1 : 0)
                         + (wc * 32 + l5) * RS + hi * 16;
        f32x16 acc0 = (f32x16)(0.f);
        f32x16 acc1 = (f32x16)(0.f);
        bf16x8 fb[2];
        fb[0] = *reinterpret_cast<const bf16x8*>(bb);
        #pragma unroll
        for (int ks = 0; ks < 16; ++ks) {
            if (ks < 15)
                fb[(ks + 1) & 1] = *reinterpret_cast<const bf16x8*>(
                    bb + (ks + 1) * 32);
            __builtin_amdgcn_s_setprio(1);
            acc0 = __builtin_amdgcn_mfma_f32_32x32x16_bf16(
                af[0][ks], fb[ks & 1], acc0, 0, 0, 0);
            acc1 = __builtin_amdgcn_mfma_f32_32x32x16_bf16(
                af[1][ks], fb[ks & 1], acc1, 0, 0, 0);
            __builtin_amdgcn_s_setprio(0);
        }

        // ---- diagonal fix (at most 2 chunks per block) ----
        if (cb < brow + 128 && cb + 64 > brow) {
            #pragma unroll
            for (int rr = 0; rr < 16; ++rr) {
                const int rloc = (rr & 3) + 8 * (rr >> 2) + 4 * hi;
                int gi = brow + wr * 64 + rloc;
                if (gi - cb - wc * 32 == l5) acc0[rr] = -diag[gi];
                gi += 32;
                if (gi - cb - wc * 32 == l5) acc1[rr] = -diag[gi];
            }
        }

        // ---- running row-max (pure register) ----
        #pragma unroll
        for (int rr = 0; rr < 16; ++rr) {
            rmx[0][rr] = fmaxf(rmx[0][rr], acc0[rr]);
            rmx[1][rr] = fmaxf(rmx[1][rr], acc1[rr]);
        }

        // ---- col-max -> clds keys ----
        {
            float v = fmaxf(acc0[0], acc1[0]);
            #pragma unroll
            for (int rr = 1; rr < 16; ++rr)
                v = fmaxf(v, fmaxf(acc0[rr], acc1[rr]));
            v = fmaxf(v, __shfl_xor(v, 32));
            if (hi == 0)
                atomicMax(&clds[wc * 32 + l5], fkey(v));
        }
    }

    // ---- final chunk colmax flush ----
    __syncthreads();
    if (wid == 0)
        atomicMax(&colmax[scol + 63 * 64 + lane], clds[lane]);

    // ---- row-max writeout ----
    #pragma unroll
    for (int mm = 0; mm < 2; ++mm)
        #pragma unroll
        for (int rr = 0; rr < 16; ++rr) {
            float v = rmx[mm][rr];
            v = fmaxf(v, __shfl_xor(v, 1));
            v = fmaxf(v, __shfl_xor(v, 2));
            v = fmaxf(v, __shfl_xor(v, 4));
            v = fmaxf(v, __shfl_xor(v, 8));
            v = fmaxf(v, __shfl_xor(v, 16));
            if (l5 == 0) {
                const int gi = brow + wr * 64 + mm * 32
                               + (rr & 3) + 8 * (rr >> 2) + 4 * hi;
                atomicMax(&rowmax[gi], fkey(v));
            }
        }
}

// ---------------- finalize: hinge + total sum ----------------
__global__ void finalize_kernel(const float* __restrict__ diag,
                                const unsigned* __restrict__ rowmax,
                                const unsigned* __restrict__ colmax,
                                float* __restrict__ out) {
    __shared__ float red[256];
    int t = threadIdx.x;
    float s = 0.f;
    for (int idx = t; idx < 2 * NN; idx += 256) {
        int i = idx & (NN - 1);
        float mx = fdec((idx < NN) ? colmax[i] : rowmax[i]);
        s += fmaxf(mx + (MARGIN_F - diag[i]), 0.f);
    }
    red[t] = s;
    __syncthreads();
    for (int off = 128; off > 0; off >>= 1) {
        if (t < off) red[t] += red[t + off];
        __syncthreads();
    }
    if (t == 0) out[0] = red[0];
}

extern "C" void kernel_launch(void* const* d_in, const int* in_sizes, int n_in,
                              void* d_out, int out_size, void* d_ws, size_t ws_size,
                              hipStream_t stream) {
    const float* imgs = reinterpret_cast<const float*>(d_in[0]);
    const float* caps = reinterpret_cast<const float*>(d_in[1]);

    float* diag      = reinterpret_cast<float*>(d_ws);
    unsigned* rowmax = reinterpret_cast<unsigned*>(diag + NN);
    unsigned* colmax = rowmax + NN;
    short* imgsb     = reinterpret_cast<short*>(colmax + NN);
    short* capsb     = imgsb + (size_t)NN * DD;

    fused_prep_kernel<<<NN / 4, 256, 0, stream>>>(imgs, caps, imgsb, capsb,
                                                  diag, rowmax, colmax);

    score_max_kernel<<<512, 256, 0, stream>>>(imgsb, capsb, diag,
                                              rowmax, colmax);

    finalize_kernel<<<1, 256, 0, stream>>>(diag, rowmax, colmax,
                                           reinterpret_cast<float*>(d_out));
}

// Round 9
// 165.230 us; speedup vs baseline: 2.4502x; 2.4502x over previous
//
#include <hip/hip_runtime.h>
#include <hip/hip_bf16.h>
#include <stdint.h>
#include <math.h>

#define NN 16384
#define DD 256
#define MARGIN_F 0.2f

typedef __attribute__((ext_vector_type(8))) short bf16x8;
typedef __attribute__((ext_vector_type(16))) float f32x16;

__device__ inline short f2bf(float f) {
    __hip_bfloat16 h = __float2bfloat16(f);
    return *reinterpret_cast<short*>(&h);
}

// monotone order-preserving float<->uint key (max via unsigned atomicMax)
__device__ inline unsigned fkey(float f) {
    unsigned b = __float_as_uint(f);
    return (b & 0x80000000u) ? ~b : (b | 0x80000000u);
}
__device__ inline float fdec(unsigned k) {
    return __uint_as_float((k & 0x80000000u) ? (k ^ 0x80000000u) : ~k);
}
#define NEG_INF_KEY 0x007FFFFFu   // fkey(-inf)

__device__ inline void gload16(const void* g, void* l) {
    __builtin_amdgcn_global_load_lds(
        (const __attribute__((address_space(1))) void*)g,
        (__attribute__((address_space(3))) void*)l, 16, 0, 0);
}

// ---------------- fused prep: f32->bf16 + diag + init maxes ----------------
__global__ __launch_bounds__(256) void fused_prep_kernel(
    const float* __restrict__ imgs, const float* __restrict__ caps,
    short* __restrict__ imgsb, short* __restrict__ capsb,
    float* __restrict__ diag, unsigned* __restrict__ rowmax,
    unsigned* __restrict__ colmax) {
    const int i = (blockIdx.x << 2) + (threadIdx.x >> 6);
    const int l = threadIdx.x & 63;
    const float4* a4 = reinterpret_cast<const float4*>(imgs + (size_t)i * DD);
    const float4* b4 = reinterpret_cast<const float4*>(caps + (size_t)i * DD);
    float4 av = a4[l];
    float4 bv = b4[l];
    short4 as, bs;
    as.x = f2bf(av.x); as.y = f2bf(av.y); as.z = f2bf(av.z); as.w = f2bf(av.w);
    bs.x = f2bf(bv.x); bs.y = f2bf(bv.y); bs.z = f2bf(bv.z); bs.w = f2bf(bv.w);
    reinterpret_cast<short4*>(imgsb + (size_t)i * DD)[l] = as;
    reinterpret_cast<short4*>(capsb + (size_t)i * DD)[l] = bs;
    float s = av.x * bv.x + av.y * bv.y + av.z * bv.z + av.w * bv.w;
    #pragma unroll
    for (int off = 32; off > 0; off >>= 1) s += __shfl_down(s, off);
    if (l == 0) {
        diag[i] = s;
        rowmax[i] = NEG_INF_KEY;
        colmax[i] = NEG_INF_KEY;
    }
}

// ---------------- main: A-resident strip kernel, 32x32x16 MFMA -------------
// R7 dataflow (proven): 512 blocks = 128 row-panels x 4 col-strips; A panel
// (128x256) staged once via gload_lds -> registers; B 64-col chunks double-
// buffered via gload_lds with XOR chunk-swizzle; counted vmcnt(8) pipeline.
// Only change vs R7: 32x32x16 MFMA (fewer issue slots, 20% less MFMA time).
__global__ __launch_bounds__(256, 2) void score_max_kernel(
    const short* __restrict__ imgsb, const short* __restrict__ capsb,
    const float* __restrict__ diag,
    unsigned* __restrict__ rowmax, unsigned* __restrict__ colmax) {

    __shared__ char lds[81920];   // [0,64K): A then 2x32KB B bufs; [64K,80K): colmax keys
    unsigned* clds = reinterpret_cast<unsigned*>(lds + 65536);

    const int bid   = blockIdx.x;
    const int panel = bid >> 2;
    const int strip = bid & 3;
    const int brow  = panel << 7;
    const int scol  = strip << 12;

    const int t    = threadIdx.x;
    const int wid  = t >> 6;
    const int lane = t & 63;
    const int wr   = wid >> 1;    // 0..1: 64-row half
    const int wc   = wid & 1;     // 0..1: 32-col half of 64-col chunk
    const int l5   = lane & 31;
    const int hi   = lane >> 5;

    // ---- init colmax keys ----
    #pragma unroll
    for (int i = 0; i < 16; ++i) clds[t + (i << 8)] = NEG_INF_KEY;

    // ---- stage A panel (64KB), chunk-swizzled: slot s of row r holds
    //      global 16B-chunk s ^ (r&7) ----
    {
        const int cs = t & 31;
        const int r0 = t >> 5;
        const int co = ((cs ^ (r0 & 7)) << 3);
        const short* src = imgsb + (((size_t)(brow + r0)) << 8) + co;
        #pragma unroll
        for (int i = 0; i < 16; ++i)
            gload16(src + ((size_t)i << 11), lds + t * 16 + i * 4096);
    }
    __syncthreads();

    // ---- A fragments to registers: af[mm][ks] (32x32x16 layout) ----
    // lane: row = mm*32 + l5 (+wr*64), k = hi*8 + ks*16 .. +8
    bf16x8 af[2][16];
    #pragma unroll
    for (int mm = 0; mm < 2; ++mm) {
        const int row = wr * 64 + mm * 32 + l5;
        const char* rb = lds + row * 512;
        const int sw = row & 7;
        #pragma unroll
        for (int ks = 0; ks < 16; ++ks) {
            const int q = hi + 2 * ks;
            af[mm][ks] = *reinterpret_cast<const bf16x8*>(rb + ((q ^ sw) << 4));
        }
    }
    __syncthreads();   // done reading A before B overwrites

    // ---- B staging geometry ----
    const int br0 = t >> 5;
    const int bco = (((t & 31) ^ (br0 & 7)) << 3);

    #define STAGEB(bo, cb) {                                                   \
        const short* s_ = capsb + (((size_t)((cb) + br0)) << 8) + bco;         \
        _Pragma("unroll")                                                      \
        for (int i_ = 0; i_ < 8; ++i_)                                         \
            gload16(s_ + ((size_t)i_ << 11), lds + (bo) + t * 16 + i_ * 4096); \
    }

    // prologue: issue stage(0) into buf0 (completion enforced at h=0 top)
    STAGEB(0, scol);

    float rmx[2][16];
    #pragma unroll
    for (int mm = 0; mm < 2; ++mm)
        #pragma unroll
        for (int rr = 0; rr < 16; ++rr) rmx[mm][rr] = -INFINITY;

    const int rr_b = wc * 32 + l5;    // B row (chunk-local col) this lane reads
    const int sw_b = rr_b & 7;
    const char* const brow_base_off = (const char*)0 + rr_b * 512;

    for (int h = 0; h < 64; ++h) {
        const int cb = scol + (h << 6);
        const char* cur = lds + ((h & 1) << 15);

        // barrier 1: all waves done reading buf[(h+1)&1] (chunk h-1)
        __builtin_amdgcn_s_barrier();
        asm volatile("" ::: "memory");
        if (h < 63) {
            STAGEB(((h + 1) & 1) << 15, cb + 64);
            // oldest-beyond-8 = stage(h): wait it; stage(h+1) stays in flight
            asm volatile("s_waitcnt vmcnt(8)" ::: "memory");
        } else {
            asm volatile("s_waitcnt vmcnt(0)" ::: "memory");
        }
        // barrier 2: stage(h) visible to all waves
        __builtin_amdgcn_s_barrier();
        asm volatile("" ::: "memory");

        f32x16 acc0 = (f32x16)(0.f);
        f32x16 acc1 = (f32x16)(0.f);

        // ---- register-double-buffered fragment pipeline, 16 k-steps ----
        const char* bb = cur + rr_b * 512;
        bf16x8 fb[2];
        fb[0] = *reinterpret_cast<const bf16x8*>(bb + ((hi ^ sw_b) << 4));
        #pragma unroll
        for (int ks = 0; ks < 16; ++ks) {
            if (ks < 15) {
                const int qn = hi + 2 * (ks + 1);
                fb[(ks + 1) & 1] = *reinterpret_cast<const bf16x8*>(
                    bb + ((qn ^ sw_b) << 4));
            }
            __builtin_amdgcn_s_setprio(1);
            acc0 = __builtin_amdgcn_mfma_f32_32x32x16_bf16(
                af[0][ks], fb[ks & 1], acc0, 0, 0, 0);
            acc1 = __builtin_amdgcn_mfma_f32_32x32x16_bf16(
                af[1][ks], fb[ks & 1], acc1, 0, 0, 0);
            __builtin_amdgcn_s_setprio(0);
        }

        // ---- diagonal fix (at most 2 chunks per block) ----
        if (cb < brow + 128 && cb + 64 > brow) {
            #pragma unroll
            for (int rr = 0; rr < 16; ++rr) {
                const int rloc = (rr & 3) + 8 * (rr >> 2) + 4 * hi;
                int gi = brow + wr * 64 + rloc;
                if (gi - cb - wc * 32 == l5) acc0[rr] = -diag[gi];
                gi += 32;
                if (gi - cb - wc * 32 == l5) acc1[rr] = -diag[gi];
            }
        }

        // ---- running row-max (pure register) ----
        #pragma unroll
        for (int rr = 0; rr < 16; ++rr) {
            rmx[0][rr] = fmaxf(rmx[0][rr], acc0[rr]);
            rmx[1][rr] = fmaxf(rmx[1][rr], acc1[rr]);
        }

        // ---- col-max -> clds keys (lane owns col cb + wc*32 + l5) ----
        {
            float v = fmaxf(acc0[0], acc1[0]);
            #pragma unroll
            for (int rr = 1; rr < 16; ++rr)
                v = fmaxf(v, fmaxf(acc0[rr], acc1[rr]));
            v = fmaxf(v, __shfl_xor(v, 32));
            if (hi == 0)
                atomicMax(&clds[(h << 6) + wc * 32 + l5], fkey(v));
        }
    }

    // ---- flush colmax keys to global ----
    __syncthreads();
    #pragma unroll
    for (int i = 0; i < 16; ++i) {
        const int c = t + (i << 8);
        atomicMax(&colmax[scol + c], clds[c]);
    }

    // ---- row-max writeout ----
    #pragma unroll
    for (int mm = 0; mm < 2; ++mm)
        #pragma unroll
        for (int rr = 0; rr < 16; ++rr) {
            float v = rmx[mm][rr];
            v = fmaxf(v, __shfl_xor(v, 1));
            v = fmaxf(v, __shfl_xor(v, 2));
            v = fmaxf(v, __shfl_xor(v, 4));
            v = fmaxf(v, __shfl_xor(v, 8));
            v = fmaxf(v, __shfl_xor(v, 16));
            if (l5 == 0) {
                const int gi = brow + wr * 64 + mm * 32
                               + (rr & 3) + 8 * (rr >> 2) + 4 * hi;
                atomicMax(&rowmax[gi], fkey(v));
            }
        }
    #undef STAGEB
}

// ---------------- finalize: hinge + total sum ----------------
__global__ __launch_bounds__(1024) void finalize_kernel(
    const float* __restrict__ diag,
    const unsigned* __restrict__ rowmax,
    const unsigned* __restrict__ colmax,
    float* __restrict__ out) {
    __shared__ float red[1024];
    int t = threadIdx.x;
    float s = 0.f;
    for (int idx = t; idx < 2 * NN; idx += 1024) {
        int i = idx & (NN - 1);
        float mx = fdec((idx < NN) ? colmax[i] : rowmax[i]);
        s += fmaxf(mx + (MARGIN_F - diag[i]), 0.f);
    }
    red[t] = s;
    __syncthreads();
    for (int off = 512; off > 0; off >>= 1) {
        if (t < off) red[t] += red[t + off];
        __syncthreads();
    }
    if (t == 0) out[0] = red[0];
}

extern "C" void kernel_launch(void* const* d_in, const int* in_sizes, int n_in,
                              void* d_out, int out_size, void* d_ws, size_t ws_size,
                              hipStream_t stream) {
    const float* imgs = reinterpret_cast<const float*>(d_in[0]);
    const float* caps = reinterpret_cast<const float*>(d_in[1]);

    float* diag      = reinterpret_cast<float*>(d_ws);
    unsigned* rowmax = reinterpret_cast<unsigned*>(diag + NN);
    unsigned* colmax = rowmax + NN;
    short* imgsb     = reinterpret_cast<short*>(colmax + NN);
    short* capsb     = imgsb + (size_t)NN * DD;

    fused_prep_kernel<<<NN / 4, 256, 0, stream>>>(imgs, caps, imgsb, capsb,
                                                  diag, rowmax, colmax);

    score_max_kernel<<<512, 256, 0, stream>>>(imgsb, capsb, diag,
                                              rowmax, colmax);

    finalize_kernel<<<1, 1024, 0, stream>>>(diag, rowmax, colmax,
                                            reinterpret_cast<float*>(d_out));
}

// Round 10
// 142.207 us; speedup vs baseline: 2.8469x; 1.1619x over previous
//
#include <hip/hip_runtime.h>
#include <hip/hip_bf16.h>
#include <stdint.h>
#include <math.h>

#define NN 16384
#define DD 256
#define MARGIN_F 0.2f

typedef __attribute__((ext_vector_type(8))) short bf16x8;
typedef __attribute__((ext_vector_type(4))) float f32x4;

__device__ inline short f2bf(float f) {
    __hip_bfloat16 h = __float2bfloat16(f);
    return *reinterpret_cast<short*>(&h);
}

// monotone order-preserving float<->uint key (max via unsigned atomicMax)
__device__ inline unsigned fkey(float f) {
    unsigned b = __float_as_uint(f);
    return (b & 0x80000000u) ? ~b : (b | 0x80000000u);
}
__device__ inline float fdec(unsigned k) {
    return __uint_as_float((k & 0x80000000u) ? (k ^ 0x80000000u) : ~k);
}
#define NEG_INF_KEY 0x007FFFFFu   // fkey(-inf)

__device__ inline void gload16(const void* g, void* l) {
    __builtin_amdgcn_global_load_lds(
        (const __attribute__((address_space(1))) void*)g,
        (__attribute__((address_space(3))) void*)l, 16, 0, 0);
}

// ---------------- fused prep: f32->bf16 + diag + init maxes ----------------
__global__ __launch_bounds__(256) void fused_prep_kernel(
    const float* __restrict__ imgs, const float* __restrict__ caps,
    short* __restrict__ imgsb, short* __restrict__ capsb,
    float* __restrict__ diag, unsigned* __restrict__ rowmax,
    unsigned* __restrict__ colmax) {
    const int i = (blockIdx.x << 2) + (threadIdx.x >> 6);
    const int l = threadIdx.x & 63;
    const float4* a4 = reinterpret_cast<const float4*>(imgs + (size_t)i * DD);
    const float4* b4 = reinterpret_cast<const float4*>(caps + (size_t)i * DD);
    float4 av = a4[l];
    float4 bv = b4[l];
    short4 as, bs;
    as.x = f2bf(av.x); as.y = f2bf(av.y); as.z = f2bf(av.z); as.w = f2bf(av.w);
    bs.x = f2bf(bv.x); bs.y = f2bf(bv.y); bs.z = f2bf(bv.z); bs.w = f2bf(bv.w);
    reinterpret_cast<short4*>(imgsb + (size_t)i * DD)[l] = as;
    reinterpret_cast<short4*>(capsb + (size_t)i * DD)[l] = bs;
    float s = av.x * bv.x + av.y * bv.y + av.z * bv.z + av.w * bv.w;
    #pragma unroll
    for (int off = 32; off > 0; off >>= 1) s += __shfl_down(s, off);
    if (l == 0) {
        diag[i] = s;
        rowmax[i] = NEG_INF_KEY;
        colmax[i] = NEG_INF_KEY;
    }
}

// ---------------- main: A-resident strip kernel (R7 skeleton) --------------
// 512 blocks = 128 row-panels x 4 col-strips. A panel (128x256) staged once
// via gload_lds -> registers; B 64-col chunks double-buffered via gload_lds
// with XOR chunk-swizzle; counted vmcnt(8) pipeline. R10: all 16 B-fragment
// ds_reads issued at chunk top (compiler streams counted lgkmcnt under the
// MFMA burst); precomputed read offsets; zero-C first MFMA (no acc memset).
__global__ __launch_bounds__(256, 2) void score_max_kernel(
    const short* __restrict__ imgsb, const short* __restrict__ capsb,
    const float* __restrict__ diag,
    unsigned* __restrict__ rowmax, unsigned* __restrict__ colmax) {

    __shared__ char lds[81920];   // [0,64K): A then 2x32KB B bufs; [64K,80K): colmax keys
    unsigned* clds = reinterpret_cast<unsigned*>(lds + 65536);

    const int bid   = blockIdx.x;
    const int panel = bid >> 2;
    const int strip = bid & 3;
    const int brow  = panel << 7;
    const int scol  = strip << 12;

    const int t    = threadIdx.x;
    const int wid  = t >> 6;
    const int lane = t & 63;
    const int wr   = wid >> 1;    // 0..1: 64-row half
    const int wc   = wid & 1;     // 0..1: 32-col half of 64-col chunk
    const int rg   = lane >> 4;   // 0..3
    const int cl   = lane & 15;   // 0..15

    // ---- init colmax keys ----
    #pragma unroll
    for (int i = 0; i < 16; ++i) clds[t + (i << 8)] = NEG_INF_KEY;

    // ---- stage A panel (64KB), chunk-swizzled: slot s of row r holds
    //      global 16B-chunk s ^ (r&7) ----
    {
        const int cs = t & 31;
        const int r0 = t >> 5;
        const int co = ((cs ^ (r0 & 7)) << 3);
        const short* src = imgsb + (((size_t)(brow + r0)) << 8) + co;
        #pragma unroll
        for (int i = 0; i < 16; ++i)
            gload16(src + ((size_t)i << 11), lds + t * 16 + i * 4096);
    }
    __syncthreads();

    // ---- A fragments to registers: af[m][ks] ----
    bf16x8 af[4][8];
    #pragma unroll
    for (int m = 0; m < 4; ++m) {
        const int row = wr * 64 + m * 16 + cl;
        const char* rb = lds + row * 512;
        const int sw = row & 7;
        #pragma unroll
        for (int ks = 0; ks < 8; ++ks) {
            const int k8 = (ks << 2) + rg;
            af[m][ks] = *reinterpret_cast<const bf16x8*>(rb + ((k8 ^ sw) << 4));
        }
    }
    __syncthreads();   // done reading A before B overwrites

    // ---- B staging geometry ----
    const int br0 = t >> 5;
    const int bco = (((t & 31) ^ (br0 & 7)) << 3);

    #define STAGEB(bo, cb) {                                                   \
        const short* s_ = capsb + (((size_t)((cb) + br0)) << 8) + bco;         \
        _Pragma("unroll")                                                      \
        for (int i_ = 0; i_ < 8; ++i_)                                         \
            gload16(s_ + ((size_t)i_ << 11), lds + (bo) + t * 16 + i_ * 4096); \
    }

    // prologue: issue stage(0) into buf0 (completion enforced at h=0 top)
    STAGEB(0, scol);

    float rmx[4][4];
    #pragma unroll
    for (int m = 0; m < 4; ++m)
        #pragma unroll
        for (int r = 0; r < 4; ++r) rmx[m][r] = -INFINITY;

    // ---- precomputed swizzled B-read byte offsets (loop-invariant) ----
    const int rr0 = wc * 32 + cl;       // B row for n=0
    const int rr1 = rr0 + 16;           // B row for n=1
    unsigned boff0[8], boff1[8];
    #pragma unroll
    for (int ks = 0; ks < 8; ++ks) {
        const int k8 = (ks << 2) + rg;
        boff0[ks] = rr0 * 512 + ((k8 ^ (rr0 & 7)) << 4);
        boff1[ks] = rr1 * 512 + ((k8 ^ (rr1 & 7)) << 4);
    }

    const f32x4 zv = (f32x4){0.f, 0.f, 0.f, 0.f};

    for (int h = 0; h < 64; ++h) {
        const int cb = scol + (h << 6);
        const char* cur = lds + ((h & 1) << 15);

        // barrier 1: all waves done reading buf[(h+1)&1] (chunk h-1)
        __builtin_amdgcn_s_barrier();
        asm volatile("" ::: "memory");
        if (h < 63) {
            STAGEB(((h + 1) & 1) << 15, cb + 64);
            // oldest-beyond-8 = stage(h): wait it; stage(h+1) stays in flight
            asm volatile("s_waitcnt vmcnt(8)" ::: "memory");
        } else {
            asm volatile("s_waitcnt vmcnt(0)" ::: "memory");
        }
        // barrier 2: stage(h) visible to all waves
        __builtin_amdgcn_s_barrier();
        asm volatile("" ::: "memory");

        // ---- issue ALL 16 B-fragment reads; compiler streams lgkmcnt ----
        bf16x8 fbv0[8], fbv1[8];
        #pragma unroll
        for (int ks = 0; ks < 8; ++ks) {
            fbv0[ks] = *reinterpret_cast<const bf16x8*>(cur + boff0[ks]);
            fbv1[ks] = *reinterpret_cast<const bf16x8*>(cur + boff1[ks]);
        }

        f32x4 acc[4][2];
        __builtin_amdgcn_s_setprio(1);
        #pragma unroll
        for (int ks = 0; ks < 8; ++ks) {
            if (ks == 0) {
                #pragma unroll
                for (int m = 0; m < 4; ++m) {
                    acc[m][0] = __builtin_amdgcn_mfma_f32_16x16x32_bf16(
                        af[m][0], fbv0[0], zv, 0, 0, 0);
                    acc[m][1] = __builtin_amdgcn_mfma_f32_16x16x32_bf16(
                        af[m][0], fbv1[0], zv, 0, 0, 0);
                }
            } else {
                #pragma unroll
                for (int m = 0; m < 4; ++m) {
                    acc[m][0] = __builtin_amdgcn_mfma_f32_16x16x32_bf16(
                        af[m][ks], fbv0[ks], acc[m][0], 0, 0, 0);
                    acc[m][1] = __builtin_amdgcn_mfma_f32_16x16x32_bf16(
                        af[m][ks], fbv1[ks], acc[m][1], 0, 0, 0);
                }
            }
        }
        __builtin_amdgcn_s_setprio(0);

        // ---- diagonal fix (at most 2 chunks per block) ----
        if (cb < brow + 128 && cb + 64 > brow) {
            #pragma unroll
            for (int m = 0; m < 4; ++m)
                #pragma unroll
                for (int r = 0; r < 4; ++r) {
                    const int i = brow + wr * 64 + m * 16 + (rg << 2) + r;
                    const int d = i - cb - wc * 32;
                    #pragma unroll
                    for (int n = 0; n < 2; ++n)
                        if (d == n * 16 + cl) acc[m][n][r] = -diag[i];
                }
        }

        // ---- running row-max (pure register) ----
        #pragma unroll
        for (int m = 0; m < 4; ++m)
            #pragma unroll
            for (int r = 0; r < 4; ++r)
                rmx[m][r] = fmaxf(rmx[m][r],
                                  fmaxf(acc[m][0][r], acc[m][1][r]));

        // ---- col-max -> clds keys ----
        #pragma unroll
        for (int n = 0; n < 2; ++n) {
            float v = acc[0][n][0];
            #pragma unroll
            for (int m = 0; m < 4; ++m)
                #pragma unroll
                for (int r = 0; r < 4; ++r)
                    v = fmaxf(v, acc[m][n][r]);
            v = fmaxf(v, __shfl_xor(v, 16));
            v = fmaxf(v, __shfl_xor(v, 32));
            if (rg == 0)
                atomicMax(&clds[(h << 6) + wc * 32 + n * 16 + cl], fkey(v));
        }
    }

    // ---- flush colmax keys to global ----
    __syncthreads();
    #pragma unroll
    for (int i = 0; i < 16; ++i) {
        const int c = t + (i << 8);
        atomicMax(&colmax[scol + c], clds[c]);
    }

    // ---- row-max writeout ----
    #pragma unroll
    for (int m = 0; m < 4; ++m)
        #pragma unroll
        for (int r = 0; r < 4; ++r) {
            float v = rmx[m][r];
            v = fmaxf(v, __shfl_xor(v, 1));
            v = fmaxf(v, __shfl_xor(v, 2));
            v = fmaxf(v, __shfl_xor(v, 4));
            v = fmaxf(v, __shfl_xor(v, 8));
            if (cl == 0)
                atomicMax(&rowmax[brow + wr * 64 + m * 16 + (rg << 2) + r],
                          fkey(v));
        }
    #undef STAGEB
}

// ---------------- finalize: hinge + total sum ----------------
__global__ __launch_bounds__(1024) void finalize_kernel(
    const float* __restrict__ diag,
    const unsigned* __restrict__ rowmax,
    const unsigned* __restrict__ colmax,
    float* __restrict__ out) {
    __shared__ float red[1024];
    int t = threadIdx.x;
    float s = 0.f;
    for (int idx = t; idx < 2 * NN; idx += 1024) {
        int i = idx & (NN - 1);
        float mx = fdec((idx < NN) ? colmax[i] : rowmax[i]);
        s += fmaxf(mx + (MARGIN_F - diag[i]), 0.f);
    }
    red[t] = s;
    __syncthreads();
    for (int off = 512; off > 0; off >>= 1) {
        if (t < off) red[t] += red[t + off];
        __syncthreads();
    }
    if (t == 0) out[0] = red[0];
}

extern "C" void kernel_launch(void* const* d_in, const int* in_sizes, int n_in,
                              void* d_out, int out_size, void* d_ws, size_t ws_size,
                              hipStream_t stream) {
    const float* imgs = reinterpret_cast<const float*>(d_in[0]);
    const float* caps = reinterpret_cast<const float*>(d_in[1]);

    float* diag      = reinterpret_cast<float*>(d_ws);
    unsigned* rowmax = reinterpret_cast<unsigned*>(diag + NN);
    unsigned* colmax = rowmax + NN;
    short* imgsb     = reinterpret_cast<short*>(colmax + NN);
    short* capsb     = imgsb + (size_t)NN * DD;

    fused_prep_kernel<<<NN / 4, 256, 0, stream>>>(imgs, caps, imgsb, capsb,
                                                  diag, rowmax, colmax);

    score_max_kernel<<<512, 256, 0, stream>>>(imgsb, capsb, diag,
                                              rowmax, colmax);

    finalize_kernel<<<1, 1024, 0, stream>>>(diag, rowmax, colmax,
                                            reinterpret_cast<float*>(d_out));
}